// Round 1
// 323.066 us; speedup vs baseline: 1.0071x; 1.0071x over previous
//
#include <hip/hip_runtime.h>
#include <math.h>

// ---------------- problem constants ----------------
constexpr int M1 = 2000, M2 = 400, BS = 8;
constexpr int AT = M1 + M2;            // 2400
constexpr int NN = BS * AT;            // 19200 nodes
constexpr int E1 = 60000, E2 = 20000, E3 = 20000;
constexpr int ET = E1 + E2 + E3;       // 100000
constexpr int H = 64, F = 64, NG = 50, L = 4, C = 4;
constexpr float CUTOFF = 10.0f;
constexpr float LOG2F_ = 0.6931471805599453f;

constexpr float SMEAR_STEP = 10.0f / 49.0f;
constexpr float SMEAR_COEFF = -12.005f;
constexpr float PI_OVER_CUT = 0.31415926535897932f; // pi/10

constexpr int NBLK = (ET + 255) / 256;  // 391

// Edge-MLP lerp table: packed bf16 pair {v_p, v_{p+1}} per (slice,p,feature).
constexpr int NT = 256;
constexpr float DSCALE = (float)(NT - 1) / CUTOFF;   // 25.5

// GEMM tiling
constexpr int TILE_M = 32;

// Fused layer kernel: node tiles. Site tiles (4 site nodes, graphs 0+2)
// then pore tiles (4 pore nodes, graph 1).
constexpr int SITE_T = M1 / 4;         // 500
constexpr int PORE_T = M2 / 4;         // 100
constexpr int NTILE  = SITE_T + PORE_T; // 600

// Candidate SRC tiles (layer-0 lin1): g0,g1 srcs < M1 (500 tiles); g2 srcs >= M1 (100)
constexpr int LT0 = M1 / 4;            // 500
constexpr int LT1 = M1 / 4;            // 500
constexpr int LT2 = M2 / 4;            // 100
constexpr int LTOT = LT0 + LT1 + LT2;  // 1100

// Merged setup kernel A block ranges
constexpr int A_TAB  = 48 * NT / 4;          // 3072 (table)
constexpr int A_INIT = NN * 64 / 256;        // 4800 (init_h)
constexpr int A_CNT  = NBLK;                 // 391  (count)
constexpr int A_CV   = 3;                    // 12 slices, 4 waves/block
constexpr int A_TOT  = A_TAB + A_INIT + A_CNT + A_CV;
// Merged setup kernel B block ranges
constexpr int B_PACK = 48 * NT * 64 / 256;   // 3072 (pack)
constexpr int B_TOT  = B_PACK + 3 + 2;       // + scan(3) + combined sort(2)

// ---------------- workspace layout (bytes) ----------------
constexpr size_t O_HA    = 0;                            // hA [NN,64] f32 (4.9MB)
constexpr size_t O_HB    = O_HA  + (size_t)NN * 64 * 4;  // hB [NN,64] f32 (4.9MB)
constexpr size_t O_XG    = O_HB  + (size_t)NN * 64 * 4;  // xg [3][AT][64][8] BF16 (7.4MB)
constexpr size_t O_DG    = O_XG  + (size_t)3 * AT * 512 * 2; // tabF scratch (setup only)
constexpr size_t O_TAB2  = O_DG  + (size_t)3 * NN * 64 * 4;  // tab2 [48,NT,64] uint (3.1MB)
constexpr size_t O_EDATA = O_TAB2 + (size_t)48 * NT * 64 * 4; // edata [ET] int4
constexpr size_t O_INT   = O_EDATA + (size_t)ET * 16;
constexpr int I_DEG  = 0;      // [3*AT] zeroed
constexpr int I_CUR  = 7200;   // [3*AT] zeroed
constexpr int I_ZEND = 14400;
constexpr int I_BASE = 14400;  // [3*(AT+1)] = 7203
constexpr int I_PERM = 21616;  // [2400] node tiles sorted by combined degree
constexpr int I_CV   = 26016;  // [12*64] float cv rows

__device__ inline float sspf(float x) {
    return fmaxf(x, 0.0f) + log1pf(expf(-fabsf(x))) - LOG2F_;
}
__device__ inline float sspf_fast(float x) {
    float t = __expf(-fabsf(x));
    return fmaxf(x, 0.0f) + __logf(1.0f + t) - LOG2F_;
}

// fp32 -> bf16 with round-to-nearest-even (bit manipulation, 4 VALU)
__device__ inline unsigned int bf16rn(float x) {
    unsigned int u = __float_as_uint(x);
    u = (u + 0x7FFFu + ((u >> 16) & 1u)) >> 16;
    return u & 0xFFFFu;
}

__device__ inline int graph_off(int g) { return g == 0 ? 0 : (g == 1 ? E1 : E1 + E2); }

__device__ inline void edge_decode(int idx, int& g, int& e,
                                   const int* ei1, const int* ei2, const int* ei3,
                                   const int* c1, const int* c2, const int* c3,
                                   const int*& ei, const int*& cl) {
    if (idx < E1)            { g = 0; e = idx;           ei = ei1; cl = c1; }
    else if (idx < E1 + E2)  { g = 1; e = idx - E1;      ei = ei2; cl = c2; }
    else                     { g = 2; e = idx - E1 - E2; ei = ei3; cl = c3; }
}

// ---------------- merged setup kernel A ----------------
__global__ __launch_bounds__(256) void k_setupA(
    const float* __restrict__ mlp_w1, const float* __restrict__ mlp_b1,
    const float* __restrict__ mlp_w2, const float* __restrict__ mlp_b2,
    float* __restrict__ tabF,
    const int* __restrict__ sites, const int* __restrict__ sites_p,
    const float* __restrict__ emb_w, const float* __restrict__ emb_p_w,
    float* __restrict__ h,
    const int* __restrict__ ei1, const int* __restrict__ ei2,
    const int* __restrict__ ei3, const int* __restrict__ c1,
    const int* __restrict__ c2, const int* __restrict__ c3,
    int* __restrict__ deg,
    const float* __restrict__ conv_b2, const float* __restrict__ blk_w,
    const float* __restrict__ blk_b, float* __restrict__ cvbuf) {
    int bid = blockIdx.x;
    int t = threadIdx.x;
    if (bid < A_TAB) {
        const int lane = t & 63;
        int w = bid * 4 + (t >> 6);
        int s = w / NT;
        int p = w - s * NT;
        int l = s % L;
        int gc = s / L;
        int c = gc % C;
        int g = gc / C;
        float d = (float)p * (CUTOFF / (float)(NT - 1));
        size_t wb = (size_t)((l * 3 + g) * C + c);
        const float* w1 = mlp_w1 + wb * NG * F;
        const float* w2 = mlp_w2 + wb * F * F;
        float w1c[NG], w2c[F];
        #pragma unroll
        for (int k = 0; k < NG; k++) w1c[k] = w1[k * F + lane];
        #pragma unroll
        for (int k = 0; k < F; k++) w2c[k] = w2[k * F + lane];
        float b1c = mlp_b1[wb * F + lane];
        float b2c = mlp_b2[wb * F + lane];
        float dd = d - (float)lane * SMEAR_STEP;
        float av = (lane < NG) ? __expf(SMEAR_COEFF * dd * dd) : 0.0f;
        float acc = b1c;
        #pragma unroll
        for (int k = 0; k < NG; k++) acc = fmaf(__shfl(av, k), w1c[k], acc);
        float tt = sspf_fast(acc);
        float acc2 = b2c;
        #pragma unroll
        for (int j = 0; j < F; j++) acc2 = fmaf(__shfl(tt, j), w2c[j], acc2);
        float ccut = 0.5f * (__cosf(d * PI_OVER_CUT) + 1.0f);
        tabF[((size_t)s * NT + p) * 64 + lane] = acc2 * ccut;
    } else if (bid < A_TAB + A_INIT) {
        int idx = (bid - A_TAB) * 256 + t;
        int f = idx & 63;
        int n = idx >> 6;
        int b = n / AT;
        int i = n - b * AT;
        float v;
        if (i < M1) v = emb_w[sites[b * M1 + i] * H + f];
        else        v = emb_p_w[sites_p[b * M2 + (i - M1)] * H + f];
        h[idx] = v;
    } else if (bid < A_TAB + A_INIT + A_CNT) {
        int idx = (bid - A_TAB - A_INIT) * 256 + t;
        if (idx < ET) {
            int g, e; const int* ei; const int* cl;
            edge_decode(idx, g, e, ei1, ei2, ei3, c1, c2, c3, ei, cl);
            atomicAdd(&deg[g * AT + ei[2 * e + 1]], 1);
        }
    } else {
        int s = (bid - A_TAB - A_INIT - A_CNT) * 4 + (t >> 6);
        int lane = t & 63;
        if (s < 12) {
            float sl = sspf(conv_b2[s * 64 + lane]);
            const float* bw = blk_w + (size_t)s * 4096;
            float a = blk_b[s * 64 + lane];
            #pragma unroll 8
            for (int k = 0; k < 64; k++)
                a = fmaf(__shfl(sl, k), bw[k * 64 + lane], a);
            cvbuf[s * 64 + lane] = a;
        }
    }
}

// ---------------- merged setup kernel B ----------------
//   [0, B_PACK): bf16-pack the table
//   [B_PACK, +3): exclusive degree scan -> base (one block per graph)
//   [B_PACK+3, +2): combined-degree counting sort -> perm
//                   block 0: site nodes by deg0+deg2 -> perm[0..2000)
//                   block 1: pore nodes by deg1      -> perm[2000..2400)
__global__ __launch_bounds__(256) void k_setupB(
    const float* __restrict__ tabF, unsigned int* __restrict__ tab2,
    const int* __restrict__ deg, int* __restrict__ base,
    int* __restrict__ perm) {
    int bid = blockIdx.x;
    int t = threadIdx.x;
    if (bid < B_PACK) {
        int idx = bid * 256 + t;
        int pc = idx & (NT * 64 - 1);
        int nxt = (pc < (NT - 1) * 64) ? idx + 64 : idx;
        unsigned int lo = bf16rn(tabF[idx]);
        unsigned int hi = bf16rn(tabF[nxt]);
        tab2[idx] = lo | (hi << 16);
    } else if (bid < B_PACK + 3) {
        const int T = 256, CH = 10;
        __shared__ int lsum[256];
        int g = bid - B_PACK;
        int loc[CH];
        int s = 0;
        #pragma unroll
        for (int i = 0; i < CH; i++) {
            int idx = t * CH + i;
            int v = (idx < AT) ? deg[g * AT + idx] : 0;
            loc[i] = s;
            s += v;
        }
        lsum[t] = s;
        __syncthreads();
        for (int off = 1; off < T; off <<= 1) {
            int v = 0;
            if (t >= off) v = lsum[t - off];
            __syncthreads();
            lsum[t] += v;
            __syncthreads();
        }
        int tb = lsum[t] - s;
        #pragma unroll
        for (int i = 0; i < CH; i++) {
            int idx = t * CH + i;
            if (idx < AT) base[g * (AT + 1) + idx] = tb + loc[i];
        }
        if (t == T - 1) base[g * (AT + 1) + AT] = lsum[T - 1];
    } else {
        __shared__ int hist[256];
        __shared__ int cur[256];
        int q = bid - B_PACK - 3;            // 0: site, 1: pore
        int cnt   = q ? M2 : M1;
        int obase = q ? M1 : 0;              // perm output base (site 2000, pore 400)
        hist[t] = 0;
        __syncthreads();
        for (int i = t; i < cnt; i += 256) {
            int key = q ? deg[AT + M1 + i] : (deg[i] + deg[2 * AT + i]);
            atomicAdd(&hist[min(key, 255)], 1);
        }
        __syncthreads();
        if (t == 0) {
            int run = 0;
            for (int k = 0; k < 256; k++) { cur[k] = run; run += hist[k]; }
        }
        __syncthreads();
        for (int i = t; i < cnt; i += 256) {
            int key = q ? deg[AT + M1 + i] : (deg[i] + deg[2 * AT + i]);
            int pos = atomicAdd(&cur[min(key, 255)], 1);
            perm[obase + pos] = q ? (M1 + i) : i;
        }
    }
}

__global__ void k_fill(const int* __restrict__ ei1, const int* __restrict__ ei2,
                       const int* __restrict__ ei3, const int* __restrict__ c1,
                       const int* __restrict__ c2, const int* __restrict__ c3,
                       const float* __restrict__ ew1, const float* __restrict__ ew2,
                       const float* __restrict__ ew3,
                       const int* __restrict__ base, int* __restrict__ cur,
                       int4* __restrict__ edata) {
    int idx = blockIdx.x * blockDim.x + threadIdx.x;
    if (idx >= ET) return;
    int g, e; const int* ei; const int* cl;
    edge_decode(idx, g, e, ei1, ei2, ei3, c1, c2, c3, ei, cl);
    const float* ew = (g == 0) ? ew1 : (g == 1 ? ew2 : ew3);
    int dst = ei[2 * e + 1];
    int src = ei[2 * e];
    int p = base[g * (AT + 1) + dst] + atomicAdd(&cur[g * AT + dst], 1);
    float t = ew[e] * DSCALE;
    int i0 = min((int)t, NT - 2);
    float fr = t - (float)i0;
    int cb = cl[e] * (L * NT) + i0;
    edata[graph_off(g) + p] = make_int4(src, cb, __float_as_int(fr), 0);
}

// ---------------- LDS-tiled GEMM machinery ----------------
__device__ inline void fma4(float acc[4], float a, const float4 b) {
    acc[0] = fmaf(a, b.x, acc[0]);
    acc[1] = fmaf(a, b.y, acc[1]);
    acc[2] = fmaf(a, b.z, acc[2]);
    acc[3] = fmaf(a, b.w, acc[3]);
}

__device__ inline void stage_B(const float* __restrict__ gB, float (*Bs)[68], int t) {
    #pragma unroll
    for (int i = 0; i < 4; i++) {
        int v = t + i * 256;
        int r = v >> 4, c4 = (v & 15) * 4;
        *(float4*)&Bs[r][c4] = *(const float4*)(gB + (size_t)r * 64 + c4);
    }
}
__device__ inline void gemm_tile(const float (*As)[68], const float (*Bs)[68],
                                 int r0, int c0, float acc0[4], float acc1[4]) {
    #pragma unroll 4
    for (int k0 = 0; k0 < 64; k0 += 4) {
        float4 a0 = *(const float4*)&As[r0][k0];
        float4 a1 = *(const float4*)&As[r0 + 1][k0];
        float4 b0 = *(const float4*)&Bs[k0][c0];
        float4 b1 = *(const float4*)&Bs[k0 + 1][c0];
        float4 b2 = *(const float4*)&Bs[k0 + 2][c0];
        float4 b3 = *(const float4*)&Bs[k0 + 3][c0];
        fma4(acc0, a0.x, b0); fma4(acc0, a0.y, b1);
        fma4(acc0, a0.z, b2); fma4(acc0, a0.w, b3);
        fma4(acc1, a1.x, b0); fma4(acc1, a1.y, b1);
        fma4(acc1, a1.z, b2); fma4(acc1, a1.w, b3);
    }
}

// Transpose-pack T[(k*8+b)][c] (f32) -> xg[((g*AT+node_k)*64+c)*8 + b] (bf16).
// Contiguous-tile variant (layer-0 lin1).
__device__ inline void xg_transpose_store(const float (*T)[68],
                                          unsigned short* __restrict__ xg,
                                          int g, int i0, int t) {
    int k = t >> 6, c = t & 63;
    unsigned int w0 = bf16rn(T[k * 8 + 0][c]) | (bf16rn(T[k * 8 + 1][c]) << 16);
    unsigned int w1 = bf16rn(T[k * 8 + 2][c]) | (bf16rn(T[k * 8 + 3][c]) << 16);
    unsigned int w2 = bf16rn(T[k * 8 + 4][c]) | (bf16rn(T[k * 8 + 5][c]) << 16);
    unsigned int w3 = bf16rn(T[k * 8 + 6][c]) | (bf16rn(T[k * 8 + 7][c]) << 16);
    unsigned short* out = xg + (((size_t)g * AT + i0 + k) * 64 + c) * 8;
    *(uint4*)out = make_uint4(w0, w1, w2, w3);
}

// Permuted-node variant (fused layer kernel).
__device__ inline void xg_tstore(const float (*T)[68],
                                 unsigned short* __restrict__ xg,
                                 int g, const int* __restrict__ perm,
                                 int pbase, int gi, int t) {
    int k = t >> 6, c = t & 63;
    int node = perm[pbase + gi * 4 + k];
    unsigned int w0 = bf16rn(T[k * 8 + 0][c]) | (bf16rn(T[k * 8 + 1][c]) << 16);
    unsigned int w1 = bf16rn(T[k * 8 + 2][c]) | (bf16rn(T[k * 8 + 3][c]) << 16);
    unsigned int w2 = bf16rn(T[k * 8 + 4][c]) | (bf16rn(T[k * 8 + 5][c]) << 16);
    unsigned int w3 = bf16rn(T[k * 8 + 6][c]) | (bf16rn(T[k * 8 + 7][c]) << 16);
    unsigned short* out = xg + (((size_t)g * AT + node) * 64 + c) * 8;
    *(uint4*)out = make_uint4(w0, w1, w2, w3);
}

// lin1 candidate-tile mapping (layer-0 only)
__device__ inline void lin1_map(int bid, int& g, int& igrp) {
    if (bid < LT0)            { g = 0; igrp = bid; }
    else if (bid < LT0 + LT1) { g = 1; igrp = bid - LT0; }
    else                      { g = 2; igrp = LT0 + (bid - LT0 - LT1); }
}

// xg[g] = h @ conv_w1[0,g]; grid LTOT (candidate src tiles only)
__global__ __launch_bounds__(256) void k_lin1t(
    const float* __restrict__ h, const float* __restrict__ conv_w1,
    unsigned short* __restrict__ xg, int l) {
    __shared__ float As[TILE_M][68];
    __shared__ float Bs[64][68];
    int t = threadIdx.x;
    int g, igrp;
    lin1_map(blockIdx.x, g, igrp);
    int i0 = igrp * 4;
    #pragma unroll
    for (int it = 0; it < 2; it++) {
        int v = t + it * 256;
        int r = v >> 4, c4 = (v & 15) * 4;
        int n = (r & 7) * AT + i0 + (r >> 3);
        *(float4*)&As[r][c4] = *(const float4*)(h + (size_t)n * 64 + c4);
    }
    stage_B(conv_w1 + (size_t)(l * 3 + g) * 4096, Bs, t);
    __syncthreads();
    int cg = t & 15, rg = t >> 4;
    int c0 = cg * 4, r0 = rg * 2;
    float acc0[4] = {0, 0, 0, 0}, acc1[4] = {0, 0, 0, 0};
    gemm_tile(As, Bs, r0, c0, acc0, acc1);
    __syncthreads();
    *(float4*)&As[r0][c0]     = make_float4(acc0[0], acc0[1], acc0[2], acc0[3]);
    *(float4*)&As[r0 + 1][c0] = make_float4(acc1[0], acc1[1], acc1[2], acc1[3]);
    __syncthreads();
    xg_transpose_store(As, xg, g, i0, t);
}

// Gather one dst's edge list into acc[8] (8 batches of feature=lane).
__device__ inline void gather_dst(const int4* __restrict__ ed, int s, int e,
                                  const unsigned int* __restrict__ tg,
                                  const unsigned short* __restrict__ xgg,
                                  int lane, float acc[8]) {
    int i = s;
    while (i < e) {
        int cnt = min(e - i, 64);
        int4 mrec = ed[i + min(lane, cnt - 1)];   // coalesced chunk prefetch
        int j = 0;
        for (; j + 2 <= cnt; j += 2) {
            int x0 = __shfl(mrec.x, j),     y0 = __shfl(mrec.y, j),     z0 = __shfl(mrec.z, j);
            int x1 = __shfl(mrec.x, j + 1), y1 = __shfl(mrec.y, j + 1), z1 = __shfl(mrec.z, j + 1);
            unsigned int u0 = tg[(size_t)y0 * 64 + lane];
            unsigned int u1 = tg[(size_t)y1 * 64 + lane];
            uint4 q0 = *(const uint4*)(xgg + ((size_t)x0 * 64 + lane) * 8);
            uint4 q1 = *(const uint4*)(xgg + ((size_t)x1 * 64 + lane) * 8);
            float lo0 = __uint_as_float(u0 << 16);
            float hi0 = __uint_as_float(u0 & 0xFFFF0000u);
            float lo1 = __uint_as_float(u1 << 16);
            float hi1 = __uint_as_float(u1 & 0xFFFF0000u);
            float wl0 = fmaf(__int_as_float(z0), hi0 - lo0, lo0);
            float wl1 = fmaf(__int_as_float(z1), hi1 - lo1, lo1);
            acc[0] = fmaf(__uint_as_float(q0.x << 16),         wl0, acc[0]);
            acc[1] = fmaf(__uint_as_float(q0.x & 0xFFFF0000u), wl0, acc[1]);
            acc[2] = fmaf(__uint_as_float(q0.y << 16),         wl0, acc[2]);
            acc[3] = fmaf(__uint_as_float(q0.y & 0xFFFF0000u), wl0, acc[3]);
            acc[4] = fmaf(__uint_as_float(q0.z << 16),         wl0, acc[4]);
            acc[5] = fmaf(__uint_as_float(q0.z & 0xFFFF0000u), wl0, acc[5]);
            acc[6] = fmaf(__uint_as_float(q0.w << 16),         wl0, acc[6]);
            acc[7] = fmaf(__uint_as_float(q0.w & 0xFFFF0000u), wl0, acc[7]);
            acc[0] = fmaf(__uint_as_float(q1.x << 16),         wl1, acc[0]);
            acc[1] = fmaf(__uint_as_float(q1.x & 0xFFFF0000u), wl1, acc[1]);
            acc[2] = fmaf(__uint_as_float(q1.y << 16),         wl1, acc[2]);
            acc[3] = fmaf(__uint_as_float(q1.y & 0xFFFF0000u), wl1, acc[3]);
            acc[4] = fmaf(__uint_as_float(q1.z << 16),         wl1, acc[4]);
            acc[5] = fmaf(__uint_as_float(q1.z & 0xFFFF0000u), wl1, acc[5]);
            acc[6] = fmaf(__uint_as_float(q1.w << 16),         wl1, acc[6]);
            acc[7] = fmaf(__uint_as_float(q1.w & 0xFFFF0000u), wl1, acc[7]);
        }
        if (j < cnt) {
            int x0 = __shfl(mrec.x, j), y0 = __shfl(mrec.y, j), z0 = __shfl(mrec.z, j);
            unsigned int u0 = tg[(size_t)y0 * 64 + lane];
            uint4 q = *(const uint4*)(xgg + ((size_t)x0 * 64 + lane) * 8);
            float lo0 = __uint_as_float(u0 << 16);
            float hi0 = __uint_as_float(u0 & 0xFFFF0000u);
            float wl = fmaf(__int_as_float(z0), hi0 - lo0, lo0);
            acc[0] = fmaf(__uint_as_float(q.x << 16),         wl, acc[0]);
            acc[1] = fmaf(__uint_as_float(q.x & 0xFFFF0000u), wl, acc[1]);
            acc[2] = fmaf(__uint_as_float(q.y << 16),         wl, acc[2]);
            acc[3] = fmaf(__uint_as_float(q.y & 0xFFFF0000u), wl, acc[3]);
            acc[4] = fmaf(__uint_as_float(q.z << 16),         wl, acc[4]);
            acc[5] = fmaf(__uint_as_float(q.z & 0xFFFF0000u), wl, acc[5]);
            acc[6] = fmaf(__uint_as_float(q.w << 16),         wl, acc[6]);
            acc[7] = fmaf(__uint_as_float(q.w & 0xFFFF0000u), wl, acc[7]);
        }
        i += cnt;
    }
}

// ---------------- FUSED per-layer kernel ----------------
// One block = one node tile (4 nodes x 8 batches = 32 rows).
// Site tiles (bid<500): gather g0+g2, two conv2->ssp->blk chains into d,
//   h' = hIn + d + cv1, then lin1(l+1) for g0 and g1 from LDS-resident h'.
// Pore tiles: gather g1, one chain, h' = hIn + d + cv0 + cv2, lin1 for g2.
// dg global round-trip eliminated; 2 kernels/layer -> 1.
__global__ __launch_bounds__(256) void k_layer(
    const int4* __restrict__ edata, const int* __restrict__ base,
    const int* __restrict__ perm,
    unsigned short* __restrict__ xg, const unsigned int* __restrict__ tab2,
    const float* __restrict__ conv_w2, const float* __restrict__ conv_b2,
    const float* __restrict__ blk_w, const float* __restrict__ blk_b,
    const float* __restrict__ conv_w1, const float* __restrict__ cvbuf,
    const float* __restrict__ hIn, float* __restrict__ hOut,
    int l, int last) {
    __shared__ float As[TILE_M][68];
    __shared__ float Bs[64][68];
    int t = threadIdx.x;
    const int lane = t & 63;
    const int wv = t >> 6;
    int bid = blockIdx.x;
    int site = (bid < SITE_T) ? 1 : 0;
    int gi = site ? (SITE_T - 1 - bid) : (PORE_T - 1 - (bid - SITE_T));  // LPT
    int pbperm = site ? 0 : M1;
    int gA = site ? 0 : 1;
    int dst = perm[pbperm + gi * 4 + wv];
    size_t pbA = (size_t)(l * 3 + gA);
    stage_B(conv_w2 + pbA * 4096, Bs, t);      // in flight during gather

    float accA[8], accB[8];
    #pragma unroll
    for (int j = 0; j < 8; j++) { accA[j] = 0.0f; accB[j] = 0.0f; }
    {
        int s = base[gA * (AT + 1) + dst];
        int e = base[gA * (AT + 1) + dst + 1];
        gather_dst(edata + graph_off(gA), s, e,
                   tab2 + ((size_t)gA * C * L + l) * NT * 64,
                   xg + (size_t)gA * AT * 512, lane, accA);
    }
    if (site) {
        int s = base[2 * (AT + 1) + dst];
        int e = base[2 * (AT + 1) + dst + 1];
        gather_dst(edata + graph_off(2), s, e,
                   tab2 + ((size_t)2 * C * L + l) * NT * 64,
                   xg + (size_t)2 * AT * 512, lane, accB);
    }
    #pragma unroll
    for (int b = 0; b < 8; b++) As[wv * 8 + b][lane] = accA[b];
    __syncthreads();                           // (1) As=accA, Bs=cw2[gA]

    int cg = t & 15, rg = t >> 4;
    int c0 = cg * 4, r0 = rg * 2;
    // chain A: conv2
    float4 cbA = *(const float4*)(conv_b2 + pbA * 64 + c0);
    float x0[4] = {cbA.x, cbA.y, cbA.z, cbA.w};
    float x1[4] = {cbA.x, cbA.y, cbA.z, cbA.w};
    gemm_tile(As, Bs, r0, c0, x0, x1);
    __syncthreads();                           // (2) gemm reads done
    *(float4*)&As[r0][c0] =
        make_float4(sspf(x0[0]), sspf(x0[1]), sspf(x0[2]), sspf(x0[3]));
    *(float4*)&As[r0 + 1][c0] =
        make_float4(sspf(x1[0]), sspf(x1[1]), sspf(x1[2]), sspf(x1[3]));
    stage_B(blk_w + pbA * 4096, Bs, t);
    __syncthreads();                           // (3) As=ssp, Bs=blkw[gA]

    // d init: hIn + biases + cv of the zero-message graph(s)
    int kk = r0 >> 3, b0 = r0 & 7;
    int nodek = perm[pbperm + gi * 4 + kk];
    size_t o0 = ((size_t)b0 * AT + nodek) * 64 + c0;
    size_t o1 = o0 + (size_t)AT * 64;
    float4 h0 = *(const float4*)(hIn + o0);
    float4 h1 = *(const float4*)(hIn + o1);
    const float* cvl = cvbuf + (size_t)l * 3 * 64;
    float4 bbA = *(const float4*)(blk_b + pbA * 64 + c0);
    float4 ex;
    if (site) {
        float4 bbB = *(const float4*)(blk_b + (size_t)(l * 3 + 2) * 64 + c0);
        float4 c1v = *(const float4*)(cvl + 64 + c0);
        ex = make_float4(bbB.x + c1v.x, bbB.y + c1v.y, bbB.z + c1v.z, bbB.w + c1v.w);
    } else {
        float4 c0v = *(const float4*)(cvl + c0);
        float4 c2v = *(const float4*)(cvl + 128 + c0);
        ex = make_float4(c0v.x + c2v.x, c0v.y + c2v.y, c0v.z + c2v.z, c0v.w + c2v.w);
    }
    float d0[4] = {h0.x + bbA.x + ex.x, h0.y + bbA.y + ex.y,
                   h0.z + bbA.z + ex.z, h0.w + bbA.w + ex.w};
    float d1[4] = {h1.x + bbA.x + ex.x, h1.y + bbA.y + ex.y,
                   h1.z + bbA.z + ex.z, h1.w + bbA.w + ex.w};
    gemm_tile(As, Bs, r0, c0, d0, d1);         // chain A: blk

    if (site) {
        __syncthreads();                       // (4) chain-A reads done
        #pragma unroll
        for (int b = 0; b < 8; b++) As[wv * 8 + b][lane] = accB[b];
        stage_B(conv_w2 + (size_t)(l * 3 + 2) * 4096, Bs, t);
        __syncthreads();                       // (5) As=accB, Bs=cw2[g2]
        float4 cbB = *(const float4*)(conv_b2 + (size_t)(l * 3 + 2) * 64 + c0);
        float y0[4] = {cbB.x, cbB.y, cbB.z, cbB.w};
        float y1[4] = {cbB.x, cbB.y, cbB.z, cbB.w};
        gemm_tile(As, Bs, r0, c0, y0, y1);
        __syncthreads();                       // (6)
        *(float4*)&As[r0][c0] =
            make_float4(sspf(y0[0]), sspf(y0[1]), sspf(y0[2]), sspf(y0[3]));
        *(float4*)&As[r0 + 1][c0] =
            make_float4(sspf(y1[0]), sspf(y1[1]), sspf(y1[2]), sspf(y1[3]));
        stage_B(blk_w + (size_t)(l * 3 + 2) * 4096, Bs, t);
        __syncthreads();                       // (7) As=ssp2, Bs=blkw[g2]
        gemm_tile(As, Bs, r0, c0, d0, d1);     // chain B: blk (accumulate)
    }

    // h' write
    *(float4*)(hOut + o0) = make_float4(d0[0], d0[1], d0[2], d0[3]);
    *(float4*)(hOut + o1) = make_float4(d1[0], d1[1], d1[2], d1[3]);
    if (last) return;

    // next-layer lin1 from LDS-resident h'
    __syncthreads();                           // (8) last gemm reads done
    *(float4*)&As[r0][c0]     = make_float4(d0[0], d0[1], d0[2], d0[3]);
    *(float4*)&As[r0 + 1][c0] = make_float4(d1[0], d1[1], d1[2], d1[3]);
    int gB = site ? 0 : 2;
    stage_B(conv_w1 + (size_t)((l + 1) * 3 + gB) * 4096, Bs, t);
    __syncthreads();                           // (9) As=h', Bs=cw1[gB]
    float p0[4] = {0, 0, 0, 0}, p1[4] = {0, 0, 0, 0};
    gemm_tile(As, Bs, r0, c0, p0, p1);
    if (site) {
        __syncthreads();                       // (10) Bs reads done
        stage_B(conv_w1 + (size_t)((l + 1) * 3 + 1) * 4096, Bs, t);
        __syncthreads();                       // (11) Bs=cw1[g1]
        float q0[4] = {0, 0, 0, 0}, q1[4] = {0, 0, 0, 0};
        gemm_tile(As, Bs, r0, c0, q0, q1);
        __syncthreads();                       // (12) As & Bs reads done
        *(float4*)&As[r0][c0]     = make_float4(p0[0], p0[1], p0[2], p0[3]);
        *(float4*)&As[r0 + 1][c0] = make_float4(p1[0], p1[1], p1[2], p1[3]);
        *(float4*)&Bs[r0][c0]     = make_float4(q0[0], q0[1], q0[2], q0[3]);
        *(float4*)&Bs[r0 + 1][c0] = make_float4(q1[0], q1[1], q1[2], q1[3]);
        __syncthreads();                       // (13) results staged
        xg_tstore(As, xg, 0, perm, pbperm, gi, t);
        xg_tstore((const float(*)[68])Bs, xg, 1, perm, pbperm, gi, t);
    } else {
        __syncthreads();                       // (10) reads done
        *(float4*)&As[r0][c0]     = make_float4(p0[0], p0[1], p0[2], p0[3]);
        *(float4*)&As[r0 + 1][c0] = make_float4(p1[0], p1[1], p1[2], p1[3]);
        __syncthreads();                       // (11)
        xg_tstore(As, xg, 2, perm, pbperm, gi, t);
    }
}

// Readout
__global__ void k_read(const float* __restrict__ h,
                       const float* __restrict__ w1, const float* __restrict__ b1,
                       const float* __restrict__ w2, const float* __restrict__ b2,
                       float* __restrict__ out) {
    int b = blockIdx.x;
    int lane = threadIdx.x & 63;
    int wv = threadIdx.x >> 6;
    __shared__ float part[4];
    float weff = 0.0f;
    #pragma unroll
    for (int j = 0; j < H / 2; j++) weff = fmaf(w1[lane * (H / 2) + j], w2[j], weff);
    float acc = 0.0f;
    for (int i = wv * (M2 / 4); i < (wv + 1) * (M2 / 4); i++)
        acc += h[((size_t)b * AT + M1 + i) * H + lane];
    float v = acc * weff;
    for (int off = 32; off; off >>= 1) v += __shfl_xor(v, off);
    if (lane == 0) part[wv] = v;
    __syncthreads();
    if (threadIdx.x == 0) {
        float bias = b2[0];
        for (int j = 0; j < H / 2; j++) bias = fmaf(b1[j], w2[j], bias);
        out[b] = part[0] + part[1] + part[2] + part[3] + (float)M2 * bias;
    }
}

// ---------------- launcher ----------------
extern "C" void kernel_launch(void* const* d_in, const int* in_sizes, int n_in,
                              void* d_out, int out_size, void* d_ws, size_t ws_size,
                              hipStream_t stream) {
    const int* sites   = (const int*)d_in[0];
    const int* sites_p = (const int*)d_in[1];
    const int* ei1 = (const int*)d_in[2];
    const float* ew1 = (const float*)d_in[3];
    const int* c1 = (const int*)d_in[4];
    const int* ei2 = (const int*)d_in[5];
    const float* ew2 = (const float*)d_in[6];
    const int* c2 = (const int*)d_in[7];
    const int* ei3 = (const int*)d_in[8];
    const float* ew3 = (const float*)d_in[9];
    const int* c3 = (const int*)d_in[10];
    const float* emb_w   = (const float*)d_in[11];
    const float* emb_p_w = (const float*)d_in[12];
    const float* mlp_w1 = (const float*)d_in[13];
    const float* mlp_b1 = (const float*)d_in[14];
    const float* mlp_w2 = (const float*)d_in[15];
    const float* mlp_b2 = (const float*)d_in[16];
    const float* conv_w1 = (const float*)d_in[17];
    const float* conv_w2 = (const float*)d_in[18];
    const float* conv_b2 = (const float*)d_in[19];
    const float* blk_w = (const float*)d_in[20];
    const float* blk_b = (const float*)d_in[21];
    const float* out_w1 = (const float*)d_in[22];
    const float* out_b1 = (const float*)d_in[23];
    const float* out_w2 = (const float*)d_in[24];
    const float* out_b2 = (const float*)d_in[25];

    char* ws = (char*)d_ws;
    float* hA   = (float*)(ws + O_HA);
    float* hB   = (float*)(ws + O_HB);
    unsigned short* xg = (unsigned short*)(ws + O_XG);
    float* tabF = (float*)(ws + O_DG);     // setup scratch (aliases old dg region)
    unsigned int* tab2 = (unsigned int*)(ws + O_TAB2);
    int4*  edata = (int4*)(ws + O_EDATA);
    int* ip    = (int*)(ws + O_INT);
    int* deg   = ip + I_DEG;
    int* cur   = ip + I_CUR;
    int* ibase = ip + I_BASE;
    int* dperm = ip + I_PERM;
    float* cvbuf = (float*)(ip + I_CV);

    hipMemsetAsync(ip, 0, (size_t)I_ZEND * sizeof(int), stream);

    k_setupA<<<A_TOT, 256, 0, stream>>>(mlp_w1, mlp_b1, mlp_w2, mlp_b2, tabF,
                                        sites, sites_p, emb_w, emb_p_w, hA,
                                        ei1, ei2, ei3, c1, c2, c3, deg,
                                        conv_b2, blk_w, blk_b, cvbuf);
    k_setupB<<<B_TOT, 256, 0, stream>>>(tabF, tab2, deg, ibase, dperm);
    k_fill<<<NBLK, 256, 0, stream>>>(ei1, ei2, ei3, c1, c2, c3, ew1, ew2, ew3,
                                     ibase, cur, edata);

    k_lin1t<<<LTOT, 256, 0, stream>>>(hA, conv_w1, xg, 0);
    float* hcur = hA;
    float* hnxt = hB;
    for (int l = 0; l < L; l++) {
        int last = (l == L - 1) ? 1 : 0;
        k_layer<<<NTILE, 256, 0, stream>>>(edata, ibase, dperm, xg, tab2,
                                           conv_w2, conv_b2, blk_w, blk_b,
                                           conv_w1, cvbuf, hcur, hnxt, l, last);
        float* tmp = hcur; hcur = hnxt; hnxt = tmp;
    }
    k_read<<<BS, 256, 0, stream>>>(hcur, out_w1, out_b1, out_w2, out_b2, (float*)d_out);
}